// Round 2
// 123.728 us; speedup vs baseline: 1.1193x; 1.1193x over previous
//
#include <hip/hip_runtime.h>
#include <hip/hip_bf16.h>

#define B_  128
#define J_  4096
#define D_  64
#define H_  128
#define E_  256
#define Z_  32

typedef __attribute__((ext_vector_type(8))) short short8;    // 8 bf16 (4 VGPRs)
typedef __attribute__((ext_vector_type(4))) float floatx4;   // MFMA C/D
typedef __attribute__((ext_vector_type(2))) float floatx2;   // packed f32 pair

// workspace layout (bytes)
#define OFF_G      0u          // G' fp32 [4096][128] = 2 MiB
#define OFF_GSTATS 2097152u    // float4 per j        = 64 KiB
#define OFF_SCAL   2162688u    // {mean(w0), mean(w0^2)}
#define OFF_W0C    2162944u    // fp32[128]
#define OFF_C3     2163456u    // fp32[128] (= hbt1)
#define OFF_W2F    2163968u    // uint4[16][64] bf16 B-frags = 16 KiB
#define OFF_POOL   2180352u    // fp32[128][64] = 32 KiB

// 1-instr RNE pack on gfx950; library fallback. low16 = bf16(a), high16 = bf16(b).
#if defined(__has_builtin)
#if __has_builtin(__builtin_amdgcn_cvt_pk_bf16_f32)
#define HAVE_CVT_PK_BF16 1
#endif
#endif

#ifdef HAVE_CVT_PK_BF16
static __device__ __forceinline__ unsigned pk2(float a, float b) {
    return __builtin_bit_cast(unsigned, __builtin_amdgcn_cvt_pk_bf16_f32(a, b));
}
#else
static __device__ __forceinline__ unsigned pk2(float a, float b) {
    __hip_bfloat162 t = __float22bfloat162_rn(make_float2(a, b));
    union { __hip_bfloat162 h; unsigned u; } c; c.h = t; return c.u;
}
#endif

// ---- DPP butterfly: 16-lane sum on the VALU pipe (no ds_bpermute).
// CDNA-VALID controls only: quad_perm xor1 (0xB1), quad_perm xor2 (0x4E),
// row_ror:4 (0x124), row_ror:8 (0x128).  row_mirror/row_half_mirror
// (0x140/0x141) are RESERVED on gfx90a+ — silently wrong (round-1 failure).
// After the two quad_perm stages every lane holds its quad-sum; adding
// rotations by 4 and 8 accumulates lanes {j, j+4, j+8, j+12} mod 16 = all
// four quads, so every lane of the 16-lane row ends with the row sum.
template<int CTRL>
static __device__ __forceinline__ float dpp_add_(float v) {
    const int t = __builtin_amdgcn_update_dpp(0, __builtin_bit_cast(int, v),
                                              CTRL, 0xF, 0xF, true);
    return v + __builtin_bit_cast(float, t);
}
static __device__ __forceinline__ float row16_sum(float v) {
    v = dpp_add_<0xB1>(v);    // quad_perm [1,0,3,2]  (xor 1)
    v = dpp_add_<0x4E>(v);    // quad_perm [2,3,0,1]  (xor 2)
    v = dpp_add_<0x124>(v);   // row_ror:4
    v = dpp_add_<0x128>(v);   // row_ror:8
    return v;
}
static __device__ __forceinline__ float wave64_sum(float v) {
    v = row16_sum(v);
    v += __shfl_xor(v, 16);
    v += __shfl_xor(v, 32);
    return v;
}

// ---- packed fp32: COMPILER-generated (gfx950 has VOP3P v_pk_*_f32; LLVM
// selects them for <2 x float> ops with guaranteed-correct modifiers —
// no hand-rolled asm to get op_sel wrong).
#if defined(__has_builtin) && __has_builtin(__builtin_elementwise_fma)
static __device__ __forceinline__ floatx2 pkfma(floatx2 a, floatx2 b, floatx2 c) {
    return __builtin_elementwise_fma(a, b, c);
}
#else
static __device__ __forceinline__ floatx2 pkfma(floatx2 a, floatx2 b, floatx2 c) {
    return a * b + c;   // HIP default -ffp-contract=fast fuses to v_pk_fma_f32
}
#endif

// relu on a packed bf16 pair: signed-i16 max vs 0 is exact relu for finite bf16
// (positive bf16 ordering == positive int16 ordering; negatives/-0 have sign
// bit set -> int16 < 0 -> clamped to 0x0000 == +0.0f). relu(rnd(x))==rnd(relu(x)).
static __device__ __forceinline__ unsigned relu2_bf16(unsigned u) {
    unsigned d; const unsigned z = 0;
    asm("v_pk_max_i16 %0, %1, %2" : "=v"(d) : "v"(u), "v"(z));
    return d;
}

// ---------------------------------------------------------------------------
// pre_kernel (1033 blocks x 128): fuses G-build + prep + pooled zeroing.
//  bid < 1024 : G'[j,h], Gstats[j] for j = bid*4 .. bid*4+3
//  bid == 1024: scal, w0c, c3, W2 bf16 B-frag pack
//  bid > 1024 : zero pooled (8 blocks x 4 KiB)
// ---------------------------------------------------------------------------
__global__ __launch_bounds__(128) void pre_kernel(
    const float* __restrict__ F, const float* __restrict__ hW1,
    const float* __restrict__ hb1, const float* __restrict__ hg1,
    const float* __restrict__ hbt1, const float* __restrict__ hW2,
    float* __restrict__ Gp, float4* __restrict__ Gstats,
    float* __restrict__ scal, float* __restrict__ w0c, float* __restrict__ c3,
    uint4* __restrict__ w2f, float4* __restrict__ zero4)
{
    __shared__ float red[24];
    const int bid = blockIdx.x;
    const int t = threadIdx.x;

    if (bid > 1024) {                        // zero pooled: 8 blocks x 4 KiB
        const int base = (bid - 1025) * 256;
        zero4[base + t]       = make_float4(0.f, 0.f, 0.f, 0.f);
        zero4[base + 128 + t] = make_float4(0.f, 0.f, 0.f, 0.f);
        return;
    }

    if (bid == 1024) {                       // prep
        const float w0h = hW1[t];
        const float s = wave64_sum(w0h);
        const float q = wave64_sum(w0h * w0h);
        if ((t & 63) == 0) { red[(t >> 6) * 2] = s; red[(t >> 6) * 2 + 1] = q; }
        __syncthreads();
        const float mw0  = (red[0] + red[2]) * (1.f / (float)H_);
        const float ew02 = (red[1] + red[3]) * (1.f / (float)H_);
        if (t == 0) { scal[0] = mw0; scal[1] = ew02; }
        w0c[t] = (hW1[t] - mw0) * hg1[t];
        c3[t]  = hbt1[t];

        const int lane = t & 63, half = t >> 6;
        const int quad = lane >> 4, col = lane & 15;
        for (int f = half; f < 16; f += 2) {
            const int kstep = f >> 2, nt = f & 3;
            const int kbase = kstep * 32 + quad * 8;
            const int n = nt * 16 + col;
            unsigned r[4];
#pragma unroll
            for (int p = 0; p < 4; p++)
                r[p] = pk2(hW2[(kbase + 2*p) * D_ + n], hW2[(kbase + 2*p + 1) * D_ + n]);
            w2f[f * 64 + lane] = make_uint4(r[0], r[1], r[2], r[3]);
        }
        return;
    }

    // ---- G part: j = bid*4 .. bid*4+3 ----
    const int j0 = bid * 4;
    const int h  = t;
    const float4* f0v = (const float4*)(F + (size_t)(j0 + 0) * D_);
    const float4* f1v = (const float4*)(F + (size_t)(j0 + 1) * D_);
    const float4* f2v = (const float4*)(F + (size_t)(j0 + 2) * D_);
    const float4* f3v = (const float4*)(F + (size_t)(j0 + 3) * D_);
    const float bias = hb1[h];
    float a0 = bias, a1 = bias, a2 = bias, a3 = bias;
#pragma unroll
    for (int dq = 0; dq < 16; dq++) {
        const float4 q0 = f0v[dq], q1 = f1v[dq], q2 = f2v[dq], q3 = f3v[dq];
        const float wa = hW1[(4*dq + 1) * H_ + h];
        const float wb = hW1[(4*dq + 2) * H_ + h];
        const float wc = hW1[(4*dq + 3) * H_ + h];
        const float wd = hW1[(4*dq + 4) * H_ + h];
        a0 = fmaf(q0.x, wa, a0); a0 = fmaf(q0.y, wb, a0);
        a0 = fmaf(q0.z, wc, a0); a0 = fmaf(q0.w, wd, a0);
        a1 = fmaf(q1.x, wa, a1); a1 = fmaf(q1.y, wb, a1);
        a1 = fmaf(q1.z, wc, a1); a1 = fmaf(q1.w, wd, a1);
        a2 = fmaf(q2.x, wa, a2); a2 = fmaf(q2.y, wb, a2);
        a2 = fmaf(q2.z, wc, a2); a2 = fmaf(q2.w, wd, a2);
        a3 = fmaf(q3.x, wa, a3); a3 = fmaf(q3.y, wb, a3);
        a3 = fmaf(q3.z, wc, a3); a3 = fmaf(q3.w, wd, a3);
    }

    const float w0h = hW1[h];
    const float g1h = hg1[h];
    float accs[4] = {a0, a1, a2, a3};
#pragma unroll
    for (int q = 0; q < 4; q++) {
        const float s1 = wave64_sum(accs[q]);
        const float s2 = wave64_sum(w0h * accs[q]);
        const float s3 = wave64_sum(accs[q] * accs[q]);
        if ((h & 63) == 0) {
            int w = h >> 6;
            red[q*6 + w*3 + 0] = s1; red[q*6 + w*3 + 1] = s2; red[q*6 + w*3 + 2] = s3;
        }
    }
    __syncthreads();
    const float inv = 1.f / (float)H_;
#pragma unroll
    for (int q = 0; q < 4; q++) {
        const float mG = (red[q*6 + 0] + red[q*6 + 3]) * inv;
        if (h == 0)
            Gstats[j0 + q] = make_float4(mG, (red[q*6+1] + red[q*6+4]) * inv,
                                             (red[q*6+2] + red[q*6+5]) * inv, 0.f);
        Gp[(j0 + q) * H_ + h] = (accs[q] - mG) * g1h;
    }
}

// ---------------------------------------------------------------------------
// main_kernel: proven round-3 structure, with
//  (a) h-computation as <2 x float> packed fma (compiler -> v_pk_fma_f32),
//  (b) 1-instr packed bf16 relu after the pack,
//  (c) 16-lane LN2 reductions via CDNA-valid DPP (0 DS ops in hot path).
// DO NOT tighten launch_bounds: (256,2) -> 128 VGPR budget is what this body
// needs; (256,4) spills (round-5: 750 MB HBM traffic, 9x slower).
// ---------------------------------------------------------------------------
#define TPW 2
#define BB  4

__global__ __launch_bounds__(256, 2) void main_kernel(
    const float* __restrict__ x, const int* __restrict__ mask,
    const float* __restrict__ Gp, const float4* __restrict__ Gstats,
    const float* __restrict__ scal,
    const float* __restrict__ w0c, const float* __restrict__ c3,
    const uint4* __restrict__ w2f,
    const float* __restrict__ hb2, const float* __restrict__ hg2,
    const float* __restrict__ hbt2,
    float* __restrict__ pooled)
{
    const int tid  = threadIdx.x;
    const int lane = tid & 63;
    const int wv   = tid >> 6;
    const int quad = lane >> 4;
    const int col  = lane & 15;
    const int b0   = blockIdx.y * BB;

    // ---- per-wave preload ----
    short8 w2r[16];
#pragma unroll
    for (int f = 0; f < 16; f++) {
        union { uint4 v; short8 s; } c; c.v = w2f[f * 64 + lane];
        w2r[f] = c.s;
    }
    floatx2 wc2[4][4], cc2[4][4];
#pragma unroll
    for (int k = 0; k < 4; k++) {
        const floatx2* wp = (const floatx2*)(w0c + k*32 + quad*8);
        const floatx2* cp = (const floatx2*)(c3  + k*32 + quad*8);
#pragma unroll
        for (int p = 0; p < 4; p++) { wc2[k][p] = wp[p]; cc2[k][p] = cp[p]; }
    }
    floatx2 b2p[4];
    float g2v[4], bt2v[4];
#pragma unroll
    for (int nt = 0; nt < 4; nt++) {
        const float hb = hb2[nt*16 + col];
        b2p[nt] = (floatx2){hb, hb};
        g2v[nt]  = hg2[nt*16 + col];
        bt2v[nt] = hbt2[nt*16 + col];
    }
    const float mw0s  = scal[0];
    const float ew02s = scal[1];

    float pool[BB][4];
#pragma unroll
    for (int bb = 0; bb < BB; bb++)
#pragma unroll
        for (int nt = 0; nt < 4; nt++) pool[bb][nt] = 0.f;

    for (int t = 0; t < TPW; t++) {
        const int tIdx = (blockIdx.x * 4 + wv) * TPW + t;
        const int j0   = tIdx * 16;
        const int rowA = j0 + col;

        // ---- tile loads (shared across BB batch rows) ----
        const float4 gs = Gstats[rowA];
        float xv[BB]; int4 mk[BB];
#pragma unroll
        for (int bb = 0; bb < BB; bb++) {
            xv[bb] = x[(size_t)(b0 + bb) * J_ + rowA];
            mk[bb] = *(const int4*)(mask + (size_t)(b0 + bb) * J_ + j0 + quad * 4);
        }
        const float* gpr = Gp + rowA * H_ + quad * 8;
        floatx2 ga2[4][4];
#pragma unroll
        for (int k = 0; k < 4; k++) {
            const floatx2* gp2 = (const floatx2*)(gpr + k*32);
#pragma unroll
            for (int p = 0; p < 4; p++) ga2[k][p] = gp2[p];
        }

#pragma unroll
        for (int bb = 0; bb < BB; bb++) {
            const float xA = xv[bb];
            const float mean = fmaf(xA, mw0s, gs.x);
            const float eh2  = fmaf(xA, fmaf(xA, ew02s, 2.f * gs.y), gs.z);
            const float r1   = rsqrtf(fmaf(-mean, mean, eh2) + 1e-5f);
            const floatx2 xAp = (floatx2){xA, xA};
            const floatx2 r1p = (floatx2){r1, r1};

            floatx4 acc[4];
#pragma unroll
            for (int nt = 0; nt < 4; nt++) acc[nt] = (floatx4){0.f, 0.f, 0.f, 0.f};

#pragma unroll
            for (int k = 0; k < 4; k++) {
                union { unsigned u[4]; short8 s; } af;
#pragma unroll
                for (int p = 0; p < 4; p++) {
                    const floatx2 tv = pkfma(pkfma(xAp, wc2[k][p], ga2[k][p]), r1p, cc2[k][p]);
                    af.u[p] = relu2_bf16(pk2(tv.x, tv.y));
                }
                acc[0] = __builtin_amdgcn_mfma_f32_16x16x32_bf16(af.s, w2r[k*4+0], acc[0], 0, 0, 0);
                acc[1] = __builtin_amdgcn_mfma_f32_16x16x32_bf16(af.s, w2r[k*4+1], acc[1], 0, 0, 0);
                acc[2] = __builtin_amdgcn_mfma_f32_16x16x32_bf16(af.s, w2r[k*4+2], acc[2], 0, 0, 0);
                acc[3] = __builtin_amdgcn_mfma_f32_16x16x32_bf16(af.s, w2r[k*4+3], acc[3], 0, 0, 0);
            }

            // ---- epilogue: bias, LN2 over d=64, relu, masked pool ----
            floatx2 vb[4][2];
#pragma unroll
            for (int nt = 0; nt < 4; nt++) {
                const floatx2 a01 = (floatx2){acc[nt][0], acc[nt][1]};
                const floatx2 a23 = (floatx2){acc[nt][2], acc[nt][3]};
                vb[nt][0] = a01 + b2p[nt];
                vb[nt][1] = a23 + b2p[nt];
            }
            floatx2 sap[2], qap[2];
#pragma unroll
            for (int rp = 0; rp < 2; rp++) {
                sap[rp] = (vb[0][rp] + vb[1][rp]) + (vb[2][rp] + vb[3][rp]);
                qap[rp] = pkfma(vb[3][rp], vb[3][rp],
                          pkfma(vb[2][rp], vb[2][rp],
                          pkfma(vb[1][rp], vb[1][rp],
                          vb[0][rp] * vb[0][rp])));
            }
            float sa[4] = {sap[0].x, sap[0].y, sap[1].x, sap[1].y};
            float qa[4] = {qap[0].x, qap[0].y, qap[1].x, qap[1].y};
#pragma unroll
            for (int r = 0; r < 4; r++) {
                sa[r] = row16_sum(sa[r]);
                qa[r] = row16_sum(qa[r]);
            }
            float mrr[4];
            mrr[0] = (mk[bb].x > 0) ? 1.f : 0.f;
            mrr[1] = (mk[bb].y > 0) ? 1.f : 0.f;
            mrr[2] = (mk[bb].z > 0) ? 1.f : 0.f;
            mrr[3] = (mk[bb].w > 0) ? 1.f : 0.f;
#pragma unroll
            for (int r = 0; r < 4; r++) {
                const float m2 = sa[r] * (1.f / 64.f);
                const float v2 = fmaf(-m2, m2, qa[r] * (1.f / 64.f));
                const float r2 = rsqrtf(v2 + 1e-5f);
#pragma unroll
                for (int nt = 0; nt < 4; nt++) {
                    const float vv  = (r & 1) ? vb[nt][r >> 1].y : vb[nt][r >> 1].x;
                    const float rg  = r2 * g2v[nt];
                    const float off = fmaf(-m2, rg, bt2v[nt]);
                    const float o   = fmaxf(0.f, fmaf(vv, rg, off));
                    pool[bb][nt] = fmaf(mrr[r], o, pool[bb][nt]);
                }
            }
        }
    }

    // reduce pools over the 4 quad-groups and write
#pragma unroll
    for (int m = 16; m < 64; m <<= 1)
#pragma unroll
        for (int bb = 0; bb < BB; bb++)
#pragma unroll
            for (int nt = 0; nt < 4; nt++)
                pool[bb][nt] += __shfl_xor(pool[bb][nt], m);

    if (lane < 16) {
#pragma unroll
        for (int bb = 0; bb < BB; bb++)
#pragma unroll
            for (int nt = 0; nt < 4; nt++)
                atomicAdd(&pooled[(size_t)(b0 + bb) * D_ + nt * 16 + lane], pool[bb][nt]);
    }
}

// ---------------------------------------------------------------------------
// final_kernel: per-b head; serial FMA chains broken into 4/8 partial
// accumulators, reductions via CDNA-valid DPP butterfly.
// ---------------------------------------------------------------------------
__global__ __launch_bounds__(256) void final_kernel(
    const float* __restrict__ pooled, const int* __restrict__ mask,
    const float* __restrict__ eW1, const float* __restrict__ eb1,
    const float* __restrict__ eW2, const float* __restrict__ eb2,
    float* __restrict__ out)
{
    __shared__ float c_lds[D_];
    __shared__ float e_lds[E_];
    __shared__ float red[8];
    __shared__ float redc[4];
    const int b = blockIdx.x;
    const int t = threadIdx.x;
    const int lane = t & 63, wid = t >> 6;

    // count observed entries in this row (coalesced int4 reads)
    {
        const int4* mrow = (const int4*)(mask + (size_t)b * J_);
        int s = 0;
#pragma unroll
        for (int i = 0; i < 4; i++) {
            const int4 v = mrow[i * 256 + t];
            s += (v.x > 0) + (v.y > 0) + (v.z > 0) + (v.w > 0);
        }
        const float fs = wave64_sum((float)s);
        if (lane == 0) redc[wid] = fs;
    }
    __syncthreads();
    const float cn = fmaxf((redc[0] + redc[1]) + (redc[2] + redc[3]), 1.f);
    if (t < D_) c_lds[t] = pooled[(size_t)b * D_ + t] / cn;
    __syncthreads();

    // layer 1: 64 -> 256 (4 partial accumulators)
    float p0 = eb1[t], p1 = 0.f, p2 = 0.f, p3 = 0.f;
#pragma unroll
    for (int d = 0; d < D_; d += 4) {
        p0 = fmaf(c_lds[d + 0], eW1[(size_t)(d + 0) * E_ + t], p0);
        p1 = fmaf(c_lds[d + 1], eW1[(size_t)(d + 1) * E_ + t], p1);
        p2 = fmaf(c_lds[d + 2], eW1[(size_t)(d + 2) * E_ + t], p2);
        p3 = fmaf(c_lds[d + 3], eW1[(size_t)(d + 3) * E_ + t], p3);
    }
    const float acc = (p0 + p1) + (p2 + p3);

    const float s  = wave64_sum(acc);
    const float s2 = wave64_sum(acc * acc);
    if ((t & 63) == 0) { red[wid * 2] = s; red[wid * 2 + 1] = s2; }
    __syncthreads();
    const float ts  = red[0] + red[2] + red[4] + red[6];
    const float ts2 = red[1] + red[3] + red[5] + red[7];
    const float m = ts * (1.f / (float)E_);
    const float v = fmaf(-m, m, ts2 * (1.f / (float)E_));
    const float r = rsqrtf(v + 1e-5f);
    e_lds[t] = fmaxf(0.f, (acc - m) * r);
    __syncthreads();

    // layer 2: 256 -> 64, first wave only (8 partial accumulators)
    if (t < 64) {
        float q0 = eb2[t], q1 = 0.f, q2 = 0.f, q3 = 0.f,
              q4 = 0.f, q5 = 0.f, q6 = 0.f, q7 = 0.f;
#pragma unroll
        for (int k = 0; k < E_; k += 8) {
            q0 = fmaf(e_lds[k + 0], eW2[(size_t)(k + 0) * 64 + t], q0);
            q1 = fmaf(e_lds[k + 1], eW2[(size_t)(k + 1) * 64 + t], q1);
            q2 = fmaf(e_lds[k + 2], eW2[(size_t)(k + 2) * 64 + t], q2);
            q3 = fmaf(e_lds[k + 3], eW2[(size_t)(k + 3) * 64 + t], q3);
            q4 = fmaf(e_lds[k + 4], eW2[(size_t)(k + 4) * 64 + t], q4);
            q5 = fmaf(e_lds[k + 5], eW2[(size_t)(k + 5) * 64 + t], q5);
            q6 = fmaf(e_lds[k + 6], eW2[(size_t)(k + 6) * 64 + t], q6);
            q7 = fmaf(e_lds[k + 7], eW2[(size_t)(k + 7) * 64 + t], q7);
        }
        const float a2 = ((q0 + q1) + (q2 + q3)) + ((q4 + q5) + (q6 + q7));

        const float u  = wave64_sum(a2);
        const float u2 = wave64_sum(a2 * a2);
        const float m2 = u * (1.f / 64.f);
        const float v2 = fmaf(-m2, m2, u2 * (1.f / 64.f));
        const float r2 = rsqrtf(v2 + 1e-5f);
        const float o  = fmaxf(0.f, (a2 - m2) * r2);
        if (t < Z_) out[(size_t)b * Z_ + t] = o;
        else        out[(size_t)B_ * Z_ + (size_t)b * Z_ + (t - Z_)] = o;
    }
}

// ---------------------------------------------------------------------------
extern "C" void kernel_launch(void* const* d_in, const int* in_sizes, int n_in,
                              void* d_out, int out_size, void* d_ws, size_t ws_size,
                              hipStream_t stream) {
    const float* x    = (const float*)d_in[0];
    const int*   mask = (const int*)d_in[1];
    const float* F    = (const float*)d_in[2];
    const float* hW1  = (const float*)d_in[3];
    const float* hb1  = (const float*)d_in[4];
    const float* hg1  = (const float*)d_in[5];
    const float* hbt1 = (const float*)d_in[6];
    const float* hW2  = (const float*)d_in[7];
    const float* hb2  = (const float*)d_in[8];
    const float* hg2  = (const float*)d_in[9];
    const float* hbt2 = (const float*)d_in[10];
    const float* eW1  = (const float*)d_in[11];
    const float* eb1  = (const float*)d_in[12];
    const float* eW2  = (const float*)d_in[13];
    const float* eb2  = (const float*)d_in[14];
    float* out = (float*)d_out;

    char* ws = (char*)d_ws;
    float*  Gp     = (float*)(ws + OFF_G);
    float4* Gstats = (float4*)(ws + OFF_GSTATS);
    float*  scal   = (float*)(ws + OFF_SCAL);
    float*  w0c    = (float*)(ws + OFF_W0C);
    float*  c3     = (float*)(ws + OFF_C3);
    uint4*  w2f    = (uint4*)(ws + OFF_W2F);
    float*  pooled = (float*)(ws + OFF_POOL);

    pre_kernel<<<1033, 128, 0, stream>>>(F, hW1, hb1, hg1, hbt1, hW2,
                                         Gp, Gstats, scal, w0c, c3, w2f,
                                         (float4*)pooled);
    main_kernel<<<dim3(J_ / (16 * 4 * TPW), B_ / BB), 256, 0, stream>>>(
        x, mask, Gp, Gstats, scal, w0c, c3, w2f, hb2, hg2, hbt2, pooled);
    final_kernel<<<B_, E_, 0, stream>>>(pooled, mask, eW1, eb1, eW2, eb2, out);
}